// Round 4
// baseline (1036.781 us; speedup 1.0000x reference)
//
#include <hip/hip_runtime.h>

// ---------------------------------------------------------------------------
// PerceiverAttention on MI355X.  B=8 T=8 N=1024 NL=64 DIM=1024 H=16 DH=64.
// R3: gemm256_kv (8-phase, audited) unchanged; attn gains T14 async-STAGE
//     split (prefetch K/V tile t+1 into regs during compute of tile t).
// ---------------------------------------------------------------------------

typedef __attribute__((ext_vector_type(8))) short s8v;   // 8 x bf16 (4 VGPR)
typedef __attribute__((ext_vector_type(4))) float f4v;   // MFMA accumulator

#define BT_ 64
#define NKV 1088

__device__ __forceinline__ ushort f2bf(float f){
  union { float f; unsigned u; } v; v.f = f;
  unsigned r = v.u + 0x7FFFu + ((v.u >> 16) & 1u);   // RNE
  return (ushort)(r >> 16);
}

__device__ __forceinline__ void gload_lds16(const ushort* g, ushort* l){
  __builtin_amdgcn_global_load_lds((const __attribute__((address_space(1))) void*)g,
                                   (__attribute__((address_space(3))) void*)l,
                                   16, 0, 0);
}

// m204 bijective XCD swizzle
__device__ __forceinline__ int xcd_swizzle(int orig, int nwg){
  int q = nwg >> 3, r = nwg & 7;
  int xcd = orig & 7, idx = orig >> 3;
  return (xcd < r ? xcd*(q+1) : r*(q+1) + (xcd-r)*q) + idx;
}

// ---------------------------------------------------------------------------
// LayerNorm -> lnA [BT][1088][1024] bf16 (media rows 0..1023, latents 1024..1087)
// ---------------------------------------------------------------------------
__global__ __launch_bounds__(256)
void ln_kernel(const float* __restrict__ media, const float* __restrict__ latents,
               const float* __restrict__ g_m, const float* __restrict__ b_m,
               const float* __restrict__ g_l, const float* __restrict__ b_l,
               ushort* __restrict__ lnA){
  int g = blockIdx.x;
  int bt = g / 1088, rr = g - bt * 1088;
  const float* src; const float* gam; const float* bet;
  if (rr < 1024){ src = media   + ((long)bt*1024 + rr)        *1024; gam = g_m; bet = b_m; }
  else          { src = latents + ((long)bt*64   + (rr-1024)) *1024; gam = g_l; bet = b_l; }
  int tid = threadIdx.x;
  float4 x = ((const float4*)src)[tid];
  float s  = x.x + x.y + x.z + x.w;
  float s2 = x.x*x.x + x.y*x.y + x.z*x.z + x.w*x.w;
  #pragma unroll
  for (int off = 32; off > 0; off >>= 1){
    s  += __shfl_down(s,  off);
    s2 += __shfl_down(s2, off);
  }
  __shared__ float ps[4], ps2[4];
  if ((tid & 63) == 0){ ps[tid>>6] = s; ps2[tid>>6] = s2; }
  __syncthreads();
  float tot  = ps[0]+ps[1]+ps[2]+ps[3];
  float tot2 = ps2[0]+ps2[1]+ps2[2]+ps2[3];
  float mean = tot * (1.f/1024.f);
  float var  = tot2 * (1.f/1024.f) - mean*mean;
  float rinv = rsqrtf(var + 1e-5f);
  float4 gm4 = ((const float4*)gam)[tid];
  float4 bt4 = ((const float4*)bet)[tid];
  ushort4 o;
  o.x = f2bf((x.x-mean)*rinv*gm4.x + bt4.x);
  o.y = f2bf((x.y-mean)*rinv*gm4.y + bt4.y);
  o.z = f2bf((x.z-mean)*rinv*gm4.z + bt4.z);
  o.w = f2bf((x.w-mean)*rinv*gm4.w + bt4.w);
  *(ushort4*)&lnA[((long)bt*1088 + rr)*1024 + tid*4] = o;
}

// ---------------------------------------------------------------------------
// Transpose-cast fp32 W[K][N] -> bf16 WT[N][K]
// ---------------------------------------------------------------------------
__global__ __launch_bounds__(256)
void transpose_cast(const float* __restrict__ W, ushort* __restrict__ WT, int K, int N){
  __shared__ float tile[32][33];
  int n0 = blockIdx.x*32, k0 = blockIdx.y*32;
  int tx = threadIdx.x & 31, ty = threadIdx.x >> 5;
  #pragma unroll
  for (int i = 0; i < 32; i += 8) tile[ty+i][tx] = W[(long)(k0+ty+i)*N + n0+tx];
  __syncthreads();
  #pragma unroll
  for (int i = 0; i < 32; i += 8) WT[(long)(n0+ty+i)*K + k0+tx] = f2bf(tile[tx][ty+i]);
}

// ---------------------------------------------------------------------------
// 256x256 8-phase bf16 GEMM for kv (M=1088 clamp-padded to 1280, N=2048,
// K=1024). Cols 0..1023 -> kvK row-major; cols 1024..2047 -> VT [bt][h][dh][1088].
// 512 threads (2x4 waves), 128 KiB dynamic LDS, T2 swizzle + T3/T4 + T5.
// ---------------------------------------------------------------------------
#define MFMAQ(MH, NH, AF, BF) \
  _Pragma("unroll") for (int m_ = 0; m_ < 4; ++m_){ \
  _Pragma("unroll") for (int n_ = 0; n_ < 2; ++n_){ \
    acc[(MH)*4+m_][(NH)*2+n_] = __builtin_amdgcn_mfma_f32_16x16x32_bf16(AF[m_*2+0], BF[n_*2+0], acc[(MH)*4+m_][(NH)*2+n_], 0,0,0); \
    acc[(MH)*4+m_][(NH)*2+n_] = __builtin_amdgcn_mfma_f32_16x16x32_bf16(AF[m_*2+1], BF[n_*2+1], acc[(MH)*4+m_][(NH)*2+n_], 0,0,0); } }

#define READA(DST, BUFB, MH) \
  _Pragma("unroll") for (int m_ = 0; m_ < 4; ++m_){ \
  _Pragma("unroll") for (int ks_ = 0; ks_ < 2; ++ks_){ \
    int R_ = wm*128 + (MH)*64 + m_*16 + l15; \
    DST[m_*2+ks_] = *(const s8v*)((BUFB) + R_*64 + (((ks_*64 + cB) ^ ((R_&7)<<4))>>1)); } }

#define READB(DST, BUFB, NH) \
  _Pragma("unroll") for (int n_ = 0; n_ < 2; ++n_){ \
  _Pragma("unroll") for (int ks_ = 0; ks_ < 2; ++ks_){ \
    int R_ = wn*64 + (NH)*32 + n_*16 + l15; \
    DST[n_*2+ks_] = *(const s8v*)((BUFB) + R_*64 + (((ks_*64 + cB) ^ ((R_&7)<<4))>>1)); } }

#define PHASE_TAIL(MH, NH, AF, BF) \
  __builtin_amdgcn_s_barrier(); \
  __builtin_amdgcn_s_setprio(1); \
  MFMAQ(MH, NH, AF, BF); \
  __builtin_amdgcn_s_setprio(0); \
  asm volatile("s_waitcnt lgkmcnt(0)" ::: "memory"); \
  __builtin_amdgcn_s_barrier();

__global__ __launch_bounds__(512, 2)
void gemm256_kv(const ushort* __restrict__ lnA, const ushort* __restrict__ WkvT,
                ushort* __restrict__ kvK, ushort* __restrict__ VT){
  extern __shared__ ushort smem[];
  ushort* As = smem;            // [2 buf][256][64]
  ushort* Bs = smem + 32768;    // [2 buf][256][64]

  int wgid = xcd_swizzle(blockIdx.x, gridDim.x);
  int batch = wgid / 40;
  int rem   = wgid - batch*40;
  int tm = rem >> 3, tn = rem & 7;     // tm 0..4, tn 0..7

  const ushort* Ab = lnA + (size_t)batch*1088*1024;
  const ushort* Bb = WkvT;

  int tid = threadIdx.x;
  int lane = tid & 63, wave = tid >> 6;
  int wm = wave >> 2, wn = wave & 3;
  int l15 = lane & 15, cB = (lane >> 4) * 16;   // fragment col byte

  auto STAGE = [&](const ushort* gbase, int grow0, int clampR, ushort* lds){
    #pragma unroll
    for (int rnd = 0; rnd < 2; ++rnd){
      int idx = rnd*512 + tid;                  // 0..1023
      int row = idx >> 3;                       // 0..127
      int colB = (idx & 7) << 4;                // physical col byte
      int lcol = colB ^ ((row & 7) << 4);       // pre-swizzled global col
      int gr = grow0 + row; gr = gr > clampR ? clampR : gr;
      gload_lds16(gbase + (size_t)gr*1024 + (lcol >> 1), lds + idx*8);
    }
  };

  f4v acc[8][4] = {};
  s8v aF0[8], aF1[8], bF0[4], bF1[4];

  // prologue: K-tile 0 (A0,A1,B0,B1) + K-tile 1 (A0,A1)
  STAGE(Ab,      tm*256,       1087, As);
  STAGE(Ab,      tm*256 + 128, 1087, As + 8192);
  STAGE(Bb,      tn*256,       2047, Bs);
  STAGE(Bb,      tn*256 + 128, 2047, Bs + 8192);
  STAGE(Ab + 64, tm*256,       1087, As + 16384);
  STAGE(Ab + 64, tm*256 + 128, 1087, As + 16384 + 8192);
  asm volatile("s_waitcnt vmcnt(4)" ::: "memory");
  __builtin_amdgcn_s_barrier();

  for (int i = 0; i < 8; ++i){
    int k1 = 2*i + 1, k2 = 2*i + 2, k3 = 2*i + 3;
    // phase 1: quadrant (0,0) from buf0; stage k1.B0 -> buf1
    READA(aF0, As, 0)
    READB(bF0, Bs, 0)
    STAGE(Bb + k1*64, tn*256, 2047, Bs + 16384);
    PHASE_TAIL(0, 0, aF0, bF0)
    // phase 2: (1,0); stage k1.B1
    READA(aF1, As, 1)
    STAGE(Bb + k1*64, tn*256 + 128, 2047, Bs + 16384 + 8192);
    PHASE_TAIL(1, 0, aF1, bF0)
    // phase 3: (0,1); stage k2.A0 -> buf0 (buf0 A-reads done at p2)
    READB(bF1, Bs, 1)
    if (k2 < 16) STAGE(Ab + k2*64, tm*256, 1087, As);
    PHASE_TAIL(0, 1, aF0, bF1)
    // phase 4: (1,1); stage k2.A1; counted vmcnt -> K-tile k1 landed
    if (k2 < 16) STAGE(Ab + k2*64, tm*256 + 128, 1087, As + 8192);
    if (i < 7) asm volatile("s_waitcnt vmcnt(4)" ::: "memory");
    else       asm volatile("s_waitcnt vmcnt(0)" ::: "memory");
    PHASE_TAIL(1, 1, aF1, bF1)
    // phase 5: (0,0) from buf1; stage k2.B0 -> buf0
    READA(aF0, As + 16384, 0)
    READB(bF0, Bs + 16384, 0)
    if (k2 < 16) STAGE(Bb + k2*64, tn*256, 2047, Bs);
    PHASE_TAIL(0, 0, aF0, bF0)
    // phase 6: (1,0); stage k2.B1
    READA(aF1, As + 16384, 1)
    if (k2 < 16) STAGE(Bb + k2*64, tn*256 + 128, 2047, Bs + 8192);
    PHASE_TAIL(1, 0, aF1, bF0)
    // phase 7: (0,1); stage k3.A0 -> buf1
    READB(bF1, Bs + 16384, 1)
    if (k3 < 16) STAGE(Ab + k3*64, tm*256, 1087, As + 16384);
    PHASE_TAIL(0, 1, aF0, bF1)
    // phase 8: (1,1); stage k3.A1; counted vmcnt -> K-tile k2 landed
    if (k3 < 16) STAGE(Ab + k3*64, tm*256 + 128, 1087, As + 16384 + 8192);
    if (i < 7) asm volatile("s_waitcnt vmcnt(4)" ::: "memory");
    else       asm volatile("s_waitcnt vmcnt(0)" ::: "memory");
    PHASE_TAIL(1, 1, aF1, bF1)
  }

  // epilogue
  int colbase = tn*256 + wn*64;
  if (tn < 4){  // K half -> kvK [bt][1088][1024]
    ushort* outp = kvK + (size_t)batch*1088*1024;
    #pragma unroll
    for (int m = 0; m < 8; ++m){
      int row0 = tm*256 + wm*128 + m*16 + ((lane>>4)<<2);
      #pragma unroll
      for (int n = 0; n < 4; ++n){
        int col = colbase + n*16 + l15;
        #pragma unroll
        for (int j = 0; j < 4; ++j){
          int row = row0 + j;
          if (row < 1088) outp[(size_t)row*1024 + col] = f2bf(acc[m][n][j]);
        }
      }
    }
  } else {      // V half -> VT [bt][16][64][1088] (transposed, ushort4)
    #pragma unroll
    for (int m = 0; m < 8; ++m){
      int kk0 = tm*256 + wm*128 + m*16 + ((lane>>4)<<2);
      if (kk0 < 1088){
        #pragma unroll
        for (int n = 0; n < 4; ++n){
          int col = colbase - 1024 + n*16 + l15;    // 0..1023
          int h = col >> 6, dh = col & 63;
          ushort4 o;
          o.x = f2bf(acc[m][n][0]); o.y = f2bf(acc[m][n][1]);
          o.z = f2bf(acc[m][n][2]); o.w = f2bf(acc[m][n][3]);
          *(ushort4*)&VT[(((size_t)batch*16 + h)*64 + dh)*1088 + kk0] = o;
        }
      }
    }
  }
}

// ---------------------------------------------------------------------------
// 128x128 m97-style GEMM for q and out (M=64 valid). A-row reads clamped.
// ---------------------------------------------------------------------------
template<int STORE_BF16>
__global__ __launch_bounds__(256)
void gemm_tn(const ushort* __restrict__ A, long strideAbatch, int clampRel,
             const ushort* __restrict__ BTm,
             void* __restrict__ C, long strideCbatch,
             int Mvalid, int N, int tiles_n, int tiles_per_batch){
  constexpr int K = 1024;
  __shared__ ushort As[128*32];
  __shared__ ushort Bs[128*32];
  int wgid = xcd_swizzle(blockIdx.x, gridDim.x);
  int batch = wgid / tiles_per_batch;
  int tile  = wgid - batch*tiles_per_batch;
  int tm = tile / tiles_n, tn = tile % tiles_n;
  const ushort* Ab = A  + (long)batch*strideAbatch + (long)tm*128*K;
  const ushort* Bb = BTm + (long)tn*128*K;
  int tid = threadIdx.x;
  int lane = tid & 63, wave = tid >> 6;
  int wm = wave >> 1, wn = wave & 1;
  f4v acc[4][4] = {};

  for (int kt = 0; kt < K/32; ++kt){
    #pragma unroll
    for (int r = 0; r < 4; ++r){
      int slot = r*256 + tid;
      const ushort* g; ushort* l;
      if (slot < 512){
        int row = slot >> 2, seg = slot & 3;
        if (row > clampRel) row = clampRel;
        g = Ab + (long)row*K + kt*32 + seg*8;
        l = &As[(r*256 + wave*64)*8];
      } else {
        int s2 = slot - 512;
        int row = s2 >> 2, seg = s2 & 3;
        g = Bb + (long)row*K + kt*32 + seg*8;
        l = &Bs[((r-2)*256 + wave*64)*8];
      }
      gload_lds16(g, l);
    }
    __syncthreads();
    s8v av[4], bv[4];
    #pragma unroll
    for (int m = 0; m < 4; ++m)
      av[m] = *(const s8v*)&As[(wm*64 + m*16 + (lane&15))*32 + (lane>>4)*8];
    #pragma unroll
    for (int n = 0; n < 4; ++n)
      bv[n] = *(const s8v*)&Bs[(wn*64 + n*16 + (lane&15))*32 + (lane>>4)*8];
    #pragma unroll
    for (int m = 0; m < 4; ++m)
      #pragma unroll
      for (int n = 0; n < 4; ++n)
        acc[m][n] = __builtin_amdgcn_mfma_f32_16x16x32_bf16(av[m], bv[n], acc[m][n], 0, 0, 0);
    __syncthreads();
  }

  long cb = (long)batch*strideCbatch;
  #pragma unroll
  for (int m = 0; m < 4; ++m){
    int row0 = tm*128 + wm*64 + m*16 + ((lane>>4)<<2);
    #pragma unroll
    for (int n = 0; n < 4; ++n){
      int col = tn*128 + wn*64 + n*16 + (lane&15);
      #pragma unroll
      for (int j = 0; j < 4; ++j){
        int row = row0 + j;
        if (row < Mvalid){
          if (STORE_BF16) ((ushort*)C)[cb + (long)row*N + col] = f2bf(acc[m][n][j]);
          else            ((float*) C)[cb + (long)row*N + col] = acc[m][n][j];
        }
      }
    }
  }
}

// ---------------------------------------------------------------------------
// Fused attention per (b,t,h): Q[64,64] K[1088,64]^T -> online softmax -> P V.
// K from kvK [bt][1088][1024]; V from VT [bt][h][64][1088] (pre-transposed).
// R3: T14 async-STAGE split — tile t+1 global->reg loads issued before the
// compute barrier of tile t; ds_writes happen after the next top barrier.
// ---------------------------------------------------------------------------
__global__ __launch_bounds__(256)
void attn_kernel(const ushort* __restrict__ qbuf, const ushort* __restrict__ kvK,
                 const ushort* __restrict__ VT, ushort* __restrict__ aout){
  __shared__ ushort Qs [64*72];
  __shared__ ushort Ks [64*72];
  __shared__ ushort Vs [64*72];
  __shared__ ushort Ps [64*72];
  int blk = xcd_swizzle(blockIdx.x, gridDim.x);
  int bt = blk >> 4, h = blk & 15;
  int tid = threadIdx.x, lane = tid & 63, wave = tid >> 6;
  int r = tid >> 2, c0 = (tid & 3) * 16;      // staging coords (row/dh, col)

  { // stage Q [64][64]
    const ushort* src = &qbuf[((long)bt*64 + r)*1024 + h*64 + c0];
    *(s8v*)&Qs[r*72 + c0]     = *(const s8v*)(src);
    *(s8v*)&Qs[r*72 + c0 + 8] = *(const s8v*)(src + 8);
  }
  float m_[4], l_[4];
  f4v accO[4] = {};
  #pragma unroll
  for (int j = 0; j < 4; ++j){ m_[j] = -1e30f; l_[j] = 0.f; }
  const long kbase = (long)bt*1088*1024;
  const long vbase = ((long)bt*16 + h)*64*1088;

  // prologue: tile 0 -> regs
  s8v kr0, kr1, vr0, vr1;
  {
    const ushort* ks = &kvK[kbase + (long)r*1024 + h*64 + c0];
    kr0 = *(const s8v*)(ks); kr1 = *(const s8v*)(ks + 8);
    const ushort* vs = &VT[vbase + (long)r*1088 + c0];
    vr0 = *(const s8v*)(vs); vr1 = *(const s8v*)(vs + 8);
  }

  for (int it = 0; it < 17; ++it){
    int t0 = it * 64;
    __syncthreads();   // prev compute's LDS reads done (publishes Q on it=0)
    // commit tile t regs -> LDS
    *(s8v*)&Ks[r*72 + c0]     = kr0;
    *(s8v*)&Ks[r*72 + c0 + 8] = kr1;
    *(s8v*)&Vs[r*72 + c0]     = vr0;
    *(s8v*)&Vs[r*72 + c0 + 8] = vr1;
    // prefetch tile t+1 (HBM latency hides under compute below)
    if (it + 1 < 17){
      const ushort* ks = &kvK[kbase + (long)(t0+64+r)*1024 + h*64 + c0];
      kr0 = *(const s8v*)(ks); kr1 = *(const s8v*)(ks + 8);
      const ushort* vs = &VT[vbase + (long)r*1088 + t0+64 + c0];
      vr0 = *(const s8v*)(vs); vr1 = *(const s8v*)(vs + 8);
    }
    __syncthreads();

    // S = Q K^T (wave's 16 q-rows x 64 kk)
    f4v s[4] = {};
    s8v aq0 = *(const s8v*)&Qs[(wave*16 + (lane&15))*72 +      (lane>>4)*8];
    s8v aq1 = *(const s8v*)&Qs[(wave*16 + (lane&15))*72 + 32 + (lane>>4)*8];
    #pragma unroll
    for (int n = 0; n < 4; ++n){
      s8v bk0 = *(const s8v*)&Ks[(n*16 + (lane&15))*72 +      (lane>>4)*8];
      s8v bk1 = *(const s8v*)&Ks[(n*16 + (lane&15))*72 + 32 + (lane>>4)*8];
      s[n] = __builtin_amdgcn_mfma_f32_16x16x32_bf16(aq0, bk0, s[n], 0, 0, 0);
      s[n] = __builtin_amdgcn_mfma_f32_16x16x32_bf16(aq1, bk1, s[n], 0, 0, 0);
    }

    // online softmax; row q = wave*16 + (lane>>4)*4 + j
    #pragma unroll
    for (int j = 0; j < 4; ++j){
      float v = fmaxf(fmaxf(s[0][j], s[1][j]), fmaxf(s[2][j], s[3][j]));
      #pragma unroll
      for (int off = 1; off < 16; off <<= 1) v = fmaxf(v, __shfl_xor(v, off));
      float mn = fmaxf(m_[j], v);
      float sc = __expf(m_[j] - mn);
      m_[j] = mn;
      float ss = 0.f;
      #pragma unroll
      for (int n = 0; n < 4; ++n){ float pv = __expf(s[n][j] - mn); s[n][j] = pv; ss += pv; }
      #pragma unroll
      for (int off = 1; off < 16; off <<= 1) ss += __shfl_xor(ss, off);
      l_[j] = l_[j]*sc + ss;
      #pragma unroll
      for (int dn = 0; dn < 4; ++dn) accO[dn][j] *= sc;
    }

    // P -> LDS (wave-private rows) for PV A-operand
    #pragma unroll
    for (int n = 0; n < 4; ++n)
      #pragma unroll
      for (int j = 0; j < 4; ++j)
        Ps[(wave*16 + ((lane>>4)<<2) + j)*72 + n*16 + (lane&15)] = f2bf(s[n][j]);

    // O += P V
    s8v pa0 = *(const s8v*)&Ps[(wave*16 + (lane&15))*72 +      (lane>>4)*8];
    s8v pa1 = *(const s8v*)&Ps[(wave*16 + (lane&15))*72 + 32 + (lane>>4)*8];
    #pragma unroll
    for (int dn = 0; dn < 4; ++dn){
      s8v bv0 = *(const s8v*)&Vs[(dn*16 + (lane&15))*72 +      (lane>>4)*8];
      s8v bv1 = *(const s8v*)&Vs[(dn*16 + (lane&15))*72 + 32 + (lane>>4)*8];
      accO[dn] = __builtin_amdgcn_mfma_f32_16x16x32_bf16(pa0, bv0, accO[dn], 0, 0, 0);
      accO[dn] = __builtin_amdgcn_mfma_f32_16x16x32_bf16(pa1, bv1, accO[dn], 0, 0, 0);
    }
  }

  // epilogue: O / (l * SCALE=8) -> aob [BT][128][1024]
  #pragma unroll
  for (int dn = 0; dn < 4; ++dn)
    #pragma unroll
    for (int j = 0; j < 4; ++j){
      int q = wave*16 + ((lane>>4)<<2) + j;
      float o = accO[dn][j] / (l_[j] * 8.0f);
      aout[((long)bt*128 + q)*1024 + h*64 + dn*16 + (lane&15)] = f2bf(o);
    }
}

// ---------------------------------------------------------------------------
// Workspace layout (total ~461 MB; 478 MB was accepted in R2's run)
// ---------------------------------------------------------------------------
static constexpr size_t SZ_LNA = (size_t)BT_*1088*1024*2;   // 142,606,336
static constexpr size_t SZ_KVK = (size_t)BT_*1088*1024*2;   // 142,606,336
static constexpr size_t SZ_VT  = (size_t)BT_*16*64*1088*2;  // 142,606,336
static constexpr size_t SZ_Q   = (size_t)BT_*64*1024*2;     //   8,388,608
static constexpr size_t SZ_AO  = (size_t)BT_*128*1024*2;    //  16,777,216
static constexpr size_t SZ_WQT = (size_t)1024*1024*2;
static constexpr size_t SZ_WKVT= (size_t)2048*1024*2;

extern "C" void kernel_launch(void* const* d_in, const int* in_sizes, int n_in,
                              void* d_out, int out_size, void* d_ws, size_t ws_size,
                              hipStream_t stream){
  const float* media   = (const float*)d_in[0];
  const float* latents = (const float*)d_in[1];
  const float* g_m     = (const float*)d_in[2];
  const float* b_m     = (const float*)d_in[3];
  const float* g_l     = (const float*)d_in[4];
  const float* b_l     = (const float*)d_in[5];
  const float* Wq      = (const float*)d_in[6];
  const float* Wkv     = (const float*)d_in[7];
  const float* Wout    = (const float*)d_in[8];

  char* ws = (char*)d_ws;
  ushort* lnA   = (ushort*)(ws);
  ushort* kvK   = (ushort*)(ws + SZ_LNA);
  ushort* VT    = (ushort*)(ws + SZ_LNA + SZ_KVK);
  ushort* qb    = (ushort*)(ws + SZ_LNA + SZ_KVK + SZ_VT);
  ushort* aob   = (ushort*)(ws + SZ_LNA + SZ_KVK + SZ_VT + SZ_Q);
  ushort* WqT   = (ushort*)(ws + SZ_LNA + SZ_KVK + SZ_VT + SZ_Q + SZ_AO);
  ushort* WkvT  = (ushort*)(ws + SZ_LNA + SZ_KVK + SZ_VT + SZ_Q + SZ_AO + SZ_WQT);
  ushort* WoutT = (ushort*)(ws + SZ_LNA + SZ_KVK + SZ_VT + SZ_Q + SZ_AO + SZ_WQT + SZ_WKVT);

  ln_kernel<<<BT_*1088, 256, 0, stream>>>(media, latents, g_m, b_m, g_l, b_l, lnA);
  transpose_cast<<<dim3(1024/32, 1024/32), 256, 0, stream>>>(Wq,   WqT,   1024, 1024);
  transpose_cast<<<dim3(2048/32, 1024/32), 256, 0, stream>>>(Wkv,  WkvT,  1024, 2048);
  transpose_cast<<<dim3(1024/32, 1024/32), 256, 0, stream>>>(Wout, WoutT, 1024, 1024);

  // kv: 5x8 tiles of 256^2 per batch, 64 batches -> 2560 blocks, 128 KiB LDS
  hipFuncSetAttribute((const void*)gemm256_kv,
                      hipFuncAttributeMaxDynamicSharedMemorySize, 131072);
  gemm256_kv<<<2560, 512, 131072, stream>>>(lnA, WkvT, kvK, VT);

  // q = latents_ln @ Wq (A = latent rows, read-clamped to 64 rows)
  gemm_tn<1><<<8*BT_, 256, 0, stream>>>(lnA + 1024*1024, (long)1088*1024, 63, WqT,
                                        qb, (long)64*1024, 64, 1024, 8, 8);

  attn_kernel<<<BT_*16, 256, 0, stream>>>(qb, kvK, VT, aob);

  // out = attn_out @ Wout -> f32 d_out
  gemm_tn<0><<<8*BT_, 256, 0, stream>>>(aob, (long)128*1024, 127, WoutT,
                                        d_out, (long)64*1024, 64, 1024, 8, 8);
}